// Round 12
// baseline (156.683 us; speedup 1.0000x reference)
//
#include <hip/hip_runtime.h>

constexpr int T = 128;
constexpr int L = 9;
constexpr float LOG2E = 1.4426950408889634f;
constexpr float LN2   = 0.6931471805599453f;

__device__ __forceinline__ float fexp2(float x){float r;asm("v_exp_f32 %0, %1":"=v"(r):"v"(x));return r;}
__device__ __forceinline__ float flog2(float x){float r;asm("v_log_f32 %0, %1":"=v"(r):"v"(x));return r;}

// async global->LDS DMA: 16B per lane, dest = uniform base + lane*16, zero VGPR cost
__device__ __forceinline__ void gl_lds16(const void* g, void* l) {
    __builtin_amdgcn_global_load_lds((const __attribute__((address_space(1))) unsigned*)g,
                                     (__attribute__((address_space(3))) unsigned*)l, 16, 0, 0);
}

// ---------- named-scalar machinery: zero local arrays ----------
#define DO_ROW(M,i) M(i,0) M(i,1) M(i,2) M(i,3) M(i,4) M(i,5) M(i,6) M(i,7) M(i,8)
#define DO_ALL(M) DO_ROW(M,0) DO_ROW(M,1) DO_ROW(M,2) DO_ROW(M,3) DO_ROW(M,4) DO_ROW(M,5) DO_ROW(M,6) DO_ROW(M,7) DO_ROW(M,8)
#define REP9(M) M(0) M(1) M(2) M(3) M(4) M(5) M(6) M(7) M(8)

// et is WAVE-UNIFORM: force SGPR class via readfirstlane (v_fma reads it as the SGPR operand)
#define DECL_ET(i,j) float et_##i##_##j;
#define INIT_ET(i,j) et_##i##_##j = __int_as_float(__builtin_amdgcn_readfirstlane(__float_as_int(fexp2(trans[(i)*9+(j)] * LOG2E))));

#define LGS(B,O0,O1,O2,O3,O4,O5,O6,O7,O8) \
  const float lg_0=B##_##O0, lg_1=B##_##O1, lg_2=B##_##O2, lg_3=B##_##O3, lg_4=B##_##O4, \
              lg_5=B##_##O5, lg_6=B##_##O6, lg_7=B##_##O7, lg_8=B##_##O8;

// 9-way register select of lg[lab]: 8 cndmask, constant tree
#define USEL const float x0_=(lab_&1)?lg_1:lg_0, x1_=(lab_&1)?lg_3:lg_2, x2_=(lab_&1)?lg_5:lg_4, x3_=(lab_&1)?lg_7:lg_6; \
  const float y0_=(lab_&2)?x1_:x0_, y1_=(lab_&2)?x3_:x2_; \
  const float z0_=(lab_&4)?y1_:y0_; \
  const float usel_=(lab_&8)?lg_8:z0_;

#define EXPJ(j) const float el_##j = fexp2(lg_##j * LOG2E);
#define MACC(j) float s_##j = a_0*et_0_##j; \
  s_##j=fmaf(a_1,et_1_##j,s_##j); s_##j=fmaf(a_2,et_2_##j,s_##j); s_##j=fmaf(a_3,et_3_##j,s_##j); \
  s_##j=fmaf(a_4,et_4_##j,s_##j); s_##j=fmaf(a_5,et_5_##j,s_##j); s_##j=fmaf(a_6,et_6_##j,s_##j); \
  s_##j=fmaf(a_7,et_7_##j,s_##j); s_##j=fmaf(a_8,et_8_##j,s_##j);
#define AUPD(j) a_##j = upd_ ? s_##j*el_##j : a_##j;

#define STEP_T(B,O0,O1,O2,O3,O4,O5,O6,O7,O8,LAB,BSEL,UPDEXPR) { \
  const int lab_ = (LAB); const bool upd_ = (UPDEXPR); \
  LGS(B,O0,O1,O2,O3,O4,O5,O6,O7,O8) \
  USEL \
  REP9(EXPJ) \
  REP9(MACC) \
  REP9(AUPD) \
  unary  += upd_ ? usel_ : 0.0f; \
  binary += upd_ ? (BSEL) : 0.0f; }

#define STEP_FIRST(B,LAB) { \
  const int lab_ = (LAB); \
  LGS(B,0,1,2,3,4,5,6,7,8) \
  USEL \
  a_0=fexp2(lg_0*LOG2E); a_1=fexp2(lg_1*LOG2E); a_2=fexp2(lg_2*LOG2E); \
  a_3=fexp2(lg_3*LOG2E); a_4=fexp2(lg_4*LOG2E); a_5=fexp2(lg_5*LOG2E); \
  a_6=fexp2(lg_6*LOG2E); a_7=fexp2(lg_7*LOG2E); a_8=fexp2(lg_8*LOG2E); \
  unary += usel_; }

// exact power-of-two renorm every 4 steps: a *= 2^-k, E += k
#define RESCALE { const unsigned ua_=__float_as_uint(a_0); const int k_=(int)(ua_>>23)-127; \
  const float sc_=__uint_as_float((254u-(ua_>>23))<<23); \
  a_0*=sc_; a_1*=sc_; a_2*=sc_; a_3*=sc_; a_4*=sc_; a_5*=sc_; a_6*=sc_; a_7*=sc_; a_8*=sc_; E+=k_; }

#define COMPUTE4(B,LABV,T0) { \
  const int l0_=(LABV).x, l1_=(LABV).y, l2_=(LABV).z, l3_=(LABV).w; \
  const float bs0_=sTrans[plab*9+l0_], bs1_=sTrans[l0_*9+l1_], bs2_=sTrans[l1_*9+l2_], bs3_=sTrans[l2_*9+l3_]; \
  STEP_T(B,0,1,2,3,4,5,6,7,8,l0_,bs0_,(((T0)+0)<len)) \
  STEP_T(B,9,10,11,12,13,14,15,16,17,l1_,bs1_,(((T0)+1)<len)) \
  STEP_T(B,18,19,20,21,22,23,24,25,26,l2_,bs2_,(((T0)+2)<len)) \
  STEP_T(B,27,28,29,30,31,32,33,34,35,l3_,bs3_,(((T0)+3)<len)) \
  plab = l3_; \
  RESCALE }

#define COMPUTE4_FIRST(B,LABV) { \
  const int l0_=(LABV).x, l1_=(LABV).y, l2_=(LABV).z, l3_=(LABV).w; \
  const float bs1_=sTrans[l0_*9+l1_], bs2_=sTrans[l1_*9+l2_], bs3_=sTrans[l2_*9+l3_]; \
  STEP_FIRST(B,l0_) \
  STEP_T(B,9,10,11,12,13,14,15,16,17,l1_,bs1_,(1<len)) \
  STEP_T(B,18,19,20,21,22,23,24,25,26,l2_,bs2_,(2<len)) \
  STEP_T(B,27,28,29,30,31,32,33,34,35,l3_,bs3_,(3<len)) \
  plab = l3_; \
  RESCALE }

// ---- async staging: 10 DMAs per block (9 logit chunks + labels), zero registers held ----
#define PREFETCH(bk,bufsel) { \
  const float* gsrc_ = gRow + (bk)*36; \
  gl_lds16(gsrc_+ 0, &stage[bufsel][0][0]); \
  gl_lds16(gsrc_+ 4, &stage[bufsel][1][0]); \
  gl_lds16(gsrc_+ 8, &stage[bufsel][2][0]); \
  gl_lds16(gsrc_+12, &stage[bufsel][3][0]); \
  gl_lds16(gsrc_+16, &stage[bufsel][4][0]); \
  gl_lds16(gsrc_+20, &stage[bufsel][5][0]); \
  gl_lds16(gsrc_+24, &stage[bufsel][6][0]); \
  gl_lds16(gsrc_+28, &stage[bufsel][7][0]); \
  gl_lds16(gsrc_+32, &stage[bufsel][8][0]); \
  gl_lds16(gLab + (bk)*4, &labStage[bufsel][0]); }

// counted wait: 10 newest (next block's DMAs) may stay in flight
#define WAIT_KEEP10 { asm volatile("s_waitcnt vmcnt(10)" ::: "memory"); __builtin_amdgcn_sched_barrier(0); }
#define WAIT_ALL    { asm volatile("s_waitcnt vmcnt(0)"  ::: "memory"); __builtin_amdgcn_sched_barrier(0); }

// declare this block's 36 floats + labels from LDS (ds_read_b128 x9, short latency)
#define LDS_BLK(B,bufsel,LABV) \
  const float4 B##c0_=stage[bufsel][0][lane], B##c1_=stage[bufsel][1][lane], B##c2_=stage[bufsel][2][lane], \
               B##c3_=stage[bufsel][3][lane], B##c4_=stage[bufsel][4][lane], B##c5_=stage[bufsel][5][lane], \
               B##c6_=stage[bufsel][6][lane], B##c7_=stage[bufsel][7][lane], B##c8_=stage[bufsel][8][lane]; \
  const float B##_0 =B##c0_.x, B##_1 =B##c0_.y, B##_2 =B##c0_.z, B##_3 =B##c0_.w, \
              B##_4 =B##c1_.x, B##_5 =B##c1_.y, B##_6 =B##c1_.z, B##_7 =B##c1_.w, \
              B##_8 =B##c2_.x, B##_9 =B##c2_.y, B##_10=B##c2_.z, B##_11=B##c2_.w, \
              B##_12=B##c3_.x, B##_13=B##c3_.y, B##_14=B##c3_.z, B##_15=B##c3_.w, \
              B##_16=B##c4_.x, B##_17=B##c4_.y, B##_18=B##c4_.z, B##_19=B##c4_.w, \
              B##_20=B##c5_.x, B##_21=B##c5_.y, B##_22=B##c5_.z, B##_23=B##c5_.w, \
              B##_24=B##c6_.x, B##_25=B##c6_.y, B##_26=B##c6_.z, B##_27=B##c6_.w, \
              B##_28=B##c7_.x, B##_29=B##c7_.y, B##_30=B##c7_.z, B##_31=B##c7_.w, \
              B##_32=B##c8_.x, B##_33=B##c8_.y, B##_34=B##c8_.z, B##_35=B##c8_.w; \
  const int4 LABV = labStage[bufsel][lane];

__global__ void __launch_bounds__(64, 1)
crf_kernel(const float* __restrict__ logits,
           const int* __restrict__ labels,
           const int* __restrict__ seq_lens,
           const float* __restrict__ trans,
           float* __restrict__ out)
{
    __shared__ float4 stage[2][9][64];   // [buf][chunk][lane] 16B units, DMA-landed
    __shared__ int4   labStage[2][64];
    __shared__ float  sTrans[81];
    const int lane = threadIdx.x;
    const int b = blockIdx.x * 64 + lane;

    for (int i = lane; i < 81; i += 64) sTrans[i] = trans[i];
    __syncthreads();

    DO_ALL(DECL_ET)
    DO_ALL(INIT_ET)

    const int len = seq_lens[b];
    const float* gRow = logits + (long)b * (T * L);
    const int*   gLab = labels + (long)b * T;

    int maxlen = len;
#pragma unroll
    for (int off = 32; off > 0; off >>= 1)
        maxlen = max(maxlen, __shfl_xor(maxlen, off, 64));
    const int nblk = (maxlen + 3) >> 2;  // 1..32, wave-uniform

    float a_0=0.f,a_1=0.f,a_2=0.f,a_3=0.f,a_4=0.f,a_5=0.f,a_6=0.f,a_7=0.f,a_8=0.f;
    float unary = 0.f, binary = 0.f;
    int E = 0, plab = 0;

    PREFETCH(0, 0);
    if (nblk > 1) { PREFETCH(1, 1); WAIT_KEEP10 }
    else          { WAIT_ALL }
    {
        LDS_BLK(b0, 0, lab0)
        COMPUTE4_FIRST(b0, lab0)
    }

    int buf = 1;
#pragma unroll 1
    for (int bk = 1; bk < nblk; ++bk) {
        if (bk + 1 < nblk) { PREFETCH(bk + 1, buf ^ 1); WAIT_KEEP10 }
        else               { WAIT_ALL }
        LDS_BLK(cb, buf, clab)
        COMPUTE4(cb, clab, bk * 4)
        buf ^= 1;
    }

    // log_norm = ln2*(log2(sum a) + E); nll = log_norm - unary - binary
    const float ssum = a_0+a_1+a_2+a_3+a_4+a_5+a_6+a_7+a_8;
    float nll = LN2 * (flog2(ssum) + (float)E) - unary - binary;

#pragma unroll
    for (int off = 32; off > 0; off >>= 1) nll += __shfl_down(nll, off, 64);
    if (lane == 0) atomicAdd(out, nll);
}

extern "C" void kernel_launch(void* const* d_in, const int* in_sizes, int n_in,
                              void* d_out, int out_size, void* d_ws, size_t ws_size,
                              hipStream_t stream)
{
    const float* logits   = (const float*)d_in[0];
    const int*   labels   = (const int*)d_in[1];
    const int*   seq_lens = (const int*)d_in[2];
    const float* trans    = (const float*)d_in[3];
    float* out = (float*)d_out;

    const int B = in_sizes[2];           // 16384
    hipMemsetAsync(d_out, 0, sizeof(float), stream);
    crf_kernel<<<dim3(B / 64), dim3(64), 0, stream>>>(logits, labels, seq_lens, trans, out);
}

// Round 13
// 155.119 us; speedup vs baseline: 1.0101x; 1.0101x over previous
//
#include <hip/hip_runtime.h>

constexpr int T = 128;
constexpr int L = 9;
constexpr float LOG2E = 1.4426950408889634f;
constexpr float LN2   = 0.6931471805599453f;

__device__ __forceinline__ float fexp2(float x){float r;asm("v_exp_f32 %0, %1":"=v"(r):"v"(x));return r;}
__device__ __forceinline__ float flog2(float x){float r;asm("v_log_f32 %0, %1":"=v"(r):"v"(x));return r;}

// async global->LDS DMA: 16B per lane, dest = uniform base + lane*16, zero VGPR cost
__device__ __forceinline__ void gl_lds16(const void* g, void* l) {
    __builtin_amdgcn_global_load_lds((const __attribute__((address_space(1))) unsigned*)g,
                                     (__attribute__((address_space(3))) unsigned*)l, 16, 0, 0);
}

// ---------- named-scalar machinery: zero local arrays ----------
#define DO_ROW(M,i) M(i,0) M(i,1) M(i,2) M(i,3) M(i,4) M(i,5) M(i,6) M(i,7) M(i,8)
#define DO_ALL(M) DO_ROW(M,0) DO_ROW(M,1) DO_ROW(M,2) DO_ROW(M,3) DO_ROW(M,4) DO_ROW(M,5) DO_ROW(M,6) DO_ROW(M,7) DO_ROW(M,8)
#define REP9(M) M(0) M(1) M(2) M(3) M(4) M(5) M(6) M(7) M(8)

// et is WAVE-UNIFORM: force SGPR class via readfirstlane (v_fma reads it as the SGPR operand)
#define DECL_ET(i,j) float et_##i##_##j;
#define INIT_ET(i,j) et_##i##_##j = __int_as_float(__builtin_amdgcn_readfirstlane(__float_as_int(fexp2(trans[(i)*9+(j)] * LOG2E))));

#define LGS(B,O0,O1,O2,O3,O4,O5,O6,O7,O8) \
  const float lg_0=B##_##O0, lg_1=B##_##O1, lg_2=B##_##O2, lg_3=B##_##O3, lg_4=B##_##O4, \
              lg_5=B##_##O5, lg_6=B##_##O6, lg_7=B##_##O7, lg_8=B##_##O8;

// 9-way register select of lg[lab]: 8 cndmask, constant tree
#define USEL const float x0_=(lab_&1)?lg_1:lg_0, x1_=(lab_&1)?lg_3:lg_2, x2_=(lab_&1)?lg_5:lg_4, x3_=(lab_&1)?lg_7:lg_6; \
  const float y0_=(lab_&2)?x1_:x0_, y1_=(lab_&2)?x3_:x2_; \
  const float z0_=(lab_&4)?y1_:y0_; \
  const float usel_=(lab_&8)?lg_8:z0_;

#define EXPJ(j) const float el_##j = fexp2(lg_##j * LOG2E);
#define MACC(j) float s_##j = a_0*et_0_##j; \
  s_##j=fmaf(a_1,et_1_##j,s_##j); s_##j=fmaf(a_2,et_2_##j,s_##j); s_##j=fmaf(a_3,et_3_##j,s_##j); \
  s_##j=fmaf(a_4,et_4_##j,s_##j); s_##j=fmaf(a_5,et_5_##j,s_##j); s_##j=fmaf(a_6,et_6_##j,s_##j); \
  s_##j=fmaf(a_7,et_7_##j,s_##j); s_##j=fmaf(a_8,et_8_##j,s_##j);
#define AUPD(j) a_##j = upd_ ? s_##j*el_##j : a_##j;

#define STEP_T(B,O0,O1,O2,O3,O4,O5,O6,O7,O8,LAB,BSEL,UPDEXPR) { \
  const int lab_ = (LAB); const bool upd_ = (UPDEXPR); \
  LGS(B,O0,O1,O2,O3,O4,O5,O6,O7,O8) \
  USEL \
  REP9(EXPJ) \
  REP9(MACC) \
  REP9(AUPD) \
  unary  += upd_ ? usel_ : 0.0f; \
  binary += upd_ ? (BSEL) : 0.0f; }

#define STEP_FIRST(B,LAB) { \
  const int lab_ = (LAB); \
  LGS(B,0,1,2,3,4,5,6,7,8) \
  USEL \
  a_0=fexp2(lg_0*LOG2E); a_1=fexp2(lg_1*LOG2E); a_2=fexp2(lg_2*LOG2E); \
  a_3=fexp2(lg_3*LOG2E); a_4=fexp2(lg_4*LOG2E); a_5=fexp2(lg_5*LOG2E); \
  a_6=fexp2(lg_6*LOG2E); a_7=fexp2(lg_7*LOG2E); a_8=fexp2(lg_8*LOG2E); \
  unary += usel_; }

// exact power-of-two renorm every 4 steps: a *= 2^-k, E += k
#define RESCALE { const unsigned ua_=__float_as_uint(a_0); const int k_=(int)(ua_>>23)-127; \
  const float sc_=__uint_as_float((254u-(ua_>>23))<<23); \
  a_0*=sc_; a_1*=sc_; a_2*=sc_; a_3*=sc_; a_4*=sc_; a_5*=sc_; a_6*=sc_; a_7*=sc_; a_8*=sc_; E+=k_; }

#define COMPUTE4(B,LABV,T0) { \
  const int l0_=(LABV).x, l1_=(LABV).y, l2_=(LABV).z, l3_=(LABV).w; \
  const float bs0_=sTrans[plab*9+l0_], bs1_=sTrans[l0_*9+l1_], bs2_=sTrans[l1_*9+l2_], bs3_=sTrans[l2_*9+l3_]; \
  STEP_T(B,0,1,2,3,4,5,6,7,8,l0_,bs0_,(((T0)+0)<len)) \
  STEP_T(B,9,10,11,12,13,14,15,16,17,l1_,bs1_,(((T0)+1)<len)) \
  STEP_T(B,18,19,20,21,22,23,24,25,26,l2_,bs2_,(((T0)+2)<len)) \
  STEP_T(B,27,28,29,30,31,32,33,34,35,l3_,bs3_,(((T0)+3)<len)) \
  plab = l3_; \
  RESCALE }

#define COMPUTE4_FIRST(B,LABV) { \
  const int l0_=(LABV).x, l1_=(LABV).y, l2_=(LABV).z, l3_=(LABV).w; \
  const float bs1_=sTrans[l0_*9+l1_], bs2_=sTrans[l1_*9+l2_], bs3_=sTrans[l2_*9+l3_]; \
  STEP_FIRST(B,l0_) \
  STEP_T(B,9,10,11,12,13,14,15,16,17,l1_,bs1_,(1<len)) \
  STEP_T(B,18,19,20,21,22,23,24,25,26,l2_,bs2_,(2<len)) \
  STEP_T(B,27,28,29,30,31,32,33,34,35,l3_,bs3_,(3<len)) \
  plab = l3_; \
  RESCALE }

// ---- async staging: 10 DMAs per block (9 logit chunks + labels) ----
#define PREFETCH(bk,bufsel) { \
  const float* gsrc_ = gRow + (bk)*36; \
  gl_lds16(gsrc_+ 0, &stage[bufsel][0][0]); \
  gl_lds16(gsrc_+ 4, &stage[bufsel][1][0]); \
  gl_lds16(gsrc_+ 8, &stage[bufsel][2][0]); \
  gl_lds16(gsrc_+12, &stage[bufsel][3][0]); \
  gl_lds16(gsrc_+16, &stage[bufsel][4][0]); \
  gl_lds16(gsrc_+20, &stage[bufsel][5][0]); \
  gl_lds16(gsrc_+24, &stage[bufsel][6][0]); \
  gl_lds16(gsrc_+28, &stage[bufsel][7][0]); \
  gl_lds16(gsrc_+32, &stage[bufsel][8][0]); \
  gl_lds16(gLab + (bk)*4, &labStage[bufsel][0]); }

// keep 3 blocks (30 DMAs) in flight: waits only for the CURRENT block's 10
#define WAIT_KEEP30 { asm volatile("s_waitcnt vmcnt(30)" ::: "memory"); __builtin_amdgcn_sched_barrier(0); }

// declare this block's 36 floats + labels from LDS (ds_read_b128 x9, short latency)
#define LDS_BLK(B,bufsel,LABV) \
  const float4 B##c0_=stage[bufsel][0][lane], B##c1_=stage[bufsel][1][lane], B##c2_=stage[bufsel][2][lane], \
               B##c3_=stage[bufsel][3][lane], B##c4_=stage[bufsel][4][lane], B##c5_=stage[bufsel][5][lane], \
               B##c6_=stage[bufsel][6][lane], B##c7_=stage[bufsel][7][lane], B##c8_=stage[bufsel][8][lane]; \
  const float B##_0 =B##c0_.x, B##_1 =B##c0_.y, B##_2 =B##c0_.z, B##_3 =B##c0_.w, \
              B##_4 =B##c1_.x, B##_5 =B##c1_.y, B##_6 =B##c1_.z, B##_7 =B##c1_.w, \
              B##_8 =B##c2_.x, B##_9 =B##c2_.y, B##_10=B##c2_.z, B##_11=B##c2_.w, \
              B##_12=B##c3_.x, B##_13=B##c3_.y, B##_14=B##c3_.z, B##_15=B##c3_.w, \
              B##_16=B##c4_.x, B##_17=B##c4_.y, B##_18=B##c4_.z, B##_19=B##c4_.w, \
              B##_20=B##c5_.x, B##_21=B##c5_.y, B##_22=B##c5_.z, B##_23=B##c5_.w, \
              B##_24=B##c6_.x, B##_25=B##c6_.y, B##_26=B##c6_.z, B##_27=B##c6_.w, \
              B##_28=B##c7_.x, B##_29=B##c7_.y, B##_30=B##c7_.z, B##_31=B##c7_.w, \
              B##_32=B##c8_.x, B##_33=B##c8_.y, B##_34=B##c8_.z, B##_35=B##c8_.w; \
  const int4 LABV = labStage[bufsel][lane];

__global__ void __launch_bounds__(64, 1)
crf_kernel(const float* __restrict__ logits,
           const int* __restrict__ labels,
           const int* __restrict__ seq_lens,
           const float* __restrict__ trans,
           float* __restrict__ out)
{
    __shared__ float4 stage[4][9][64];   // 4 buffers: prefetch depth 3
    __shared__ int4   labStage[4][64];
    __shared__ float  sTrans[81];
    const int lane = threadIdx.x;
    const int b = blockIdx.x * 64 + lane;

    for (int i = lane; i < 81; i += 64) sTrans[i] = trans[i];
    __syncthreads();

    DO_ALL(DECL_ET)
    DO_ALL(INIT_ET)

    const int len = seq_lens[b];
    const float* gRow = logits + (long)b * (T * L);
    const int*   gLab = labels + (long)b * T;

    int maxlen = len;
#pragma unroll
    for (int off = 32; off > 0; off >>= 1)
        maxlen = max(maxlen, __shfl_xor(maxlen, off, 64));
    const int nblk = (maxlen + 3) >> 2;  // 1..32, wave-uniform
    const int last = nblk - 1;

    float a_0=0.f,a_1=0.f,a_2=0.f,a_3=0.f,a_4=0.f,a_5=0.f,a_6=0.f,a_7=0.f,a_8=0.f;
    float unary = 0.f, binary = 0.f;
    int E = 0, plab = 0;

    // prologue: blocks 0..2 (clamped; redundant copies for small nblk are never read)
    PREFETCH(0, 0);
    PREFETCH(min(1, last), 1);
    PREFETCH(min(2, last), 2);

    // iteration 0 peeled (STEP_FIRST)
    PREFETCH(min(3, last), 3);
    WAIT_KEEP30
    {
        LDS_BLK(b0, 0, lab0)
        COMPUTE4_FIRST(b0, lab0)
    }

#pragma unroll 1
    for (int bk = 1; bk < nblk; ++bk) {
        const int pf = bk + 3 <= last ? bk + 3 : last;   // clamp: always exactly 10 DMAs/iter
        PREFETCH(pf, (bk + 3) & 3);
        WAIT_KEEP30
        LDS_BLK(cb, bk & 3, clab)
        COMPUTE4(cb, clab, bk * 4)
    }

    // log_norm = ln2*(log2(sum a) + E); nll = log_norm - unary - binary
    const float ssum = a_0+a_1+a_2+a_3+a_4+a_5+a_6+a_7+a_8;
    float nll = LN2 * (flog2(ssum) + (float)E) - unary - binary;

#pragma unroll
    for (int off = 32; off > 0; off >>= 1) nll += __shfl_down(nll, off, 64);
    if (lane == 0) atomicAdd(out, nll);
}

extern "C" void kernel_launch(void* const* d_in, const int* in_sizes, int n_in,
                              void* d_out, int out_size, void* d_ws, size_t ws_size,
                              hipStream_t stream)
{
    const float* logits   = (const float*)d_in[0];
    const int*   labels   = (const int*)d_in[1];
    const int*   seq_lens = (const int*)d_in[2];
    const float* trans    = (const float*)d_in[3];
    float* out = (float*)d_out;

    const int B = in_sizes[2];           // 16384
    hipMemsetAsync(d_out, 0, sizeof(float), stream);
    crf_kernel<<<dim3(B / 64), dim3(64), 0, stream>>>(logits, labels, seq_lens, trans, out);
}